// Round 16
// baseline (39.544 us; speedup 1.0000x reference)
//
#include <hip/hip_runtime.h>
#include <hip/hip_bf16.h>

// Problem: B=8, CIN=8, COUT=8, NX=NT=512, M1=M2=4.
// out[b,o,z,i] = Re( sum_{m,kw} c2[b,o,m,kw] e^{2pi i (m z + kw i)/512} ) / 65536
// *** R16 = MEASUREMENT ROUND ***: exact R13 structure, but k_mix_eval is
// launched TWICE (idempotent rewrite). dur16 - dur13 ~= T(k_mix_eval) + ~1us
// boundary. Locates the unexplained ~8us (read path vs write path).
// Ledger: R13=R14=R15=25.6 (structure-invariant); NT stores +4us (R11);
// grid.sync ~100us (R5); kernel split -2us (R12).

#define PI2 6.283185307179586f

typedef float vfloat4 __attribute__((ext_vector_type(4)));   // native clang vector

// fold-reduce: lanes with (lane&msk)==0 end holding u+partner_u; lanes with
// (lane&msk)!=0 end holding v+partner_v.
__device__ __forceinline__ float foldred(float u, float v, int msk, int lane) {
    float send = (lane & msk) ? u : v;
    float recv = __shfl_xor(send, msk, 64);
    return ((lane & msk) ? v : u) + recv;
}

// full fold of 4 complex accumulators -> every lane holds (kw=(l>>1)&3, ri=l&1)
__device__ __forceinline__ float fold8(const float* ar, const float* ai, int lane) {
    float A0 = foldred(ar[0], ai[0], 1, lane);
    float A1 = foldred(ar[1], ai[1], 1, lane);
    float A2 = foldred(ar[2], ai[2], 1, lane);
    float A3 = foldred(ar[3], ai[3], 1, lane);
    float B0 = foldred(A0, A1, 2, lane);
    float B1 = foldred(A2, A3, 2, lane);
    float C  = foldred(B0, B1, 4, lane);
    C += __shfl_xor(C, 8, 64);
    C += __shfl_xor(C, 16, 64);
    C += __shfl_xor(C, 32, 64);
    return C;
}

// ---- K_A: t-DFT + y-twiddle, 4 rows per wave, 16-row block sum. 1024x256. ----
__global__ __launch_bounds__(256) void k_dft_t(const float* __restrict__ x,
                                               float* __restrict__ Yg) {
    __shared__ float vals[4][64];
    int lane = threadIdx.x & 63;
    int w    = threadIdx.x >> 6;         // 0..3
    int bc   = blockIdx.x >> 4;          // b*8+ci
    int g    = blockIdx.x & 15;
    int y0   = g * 16 + w * 4;           // this wave: xs-rows y0..y0+3

    const float* base = x + (size_t)bc * 512 * 512;

    vfloat4 A0[4], A1[4];
#pragma unroll
    for (int r = 0; r < 4; ++r) {
        const vfloat4* row = (const vfloat4*)(base + (size_t)(2 * (y0 + r)) * 512);
        A0[r] = __builtin_nontemporal_load(&row[lane]);
        A1[r] = __builtin_nontemporal_load(&row[lane + 64]);
    }

    float s, c;
    sincosf((PI2 / 128.0f) * (float)lane, &s, &c);
    float er[4], ei[4], orE[4], oiE[4];
    er[0] = 1.f; ei[0] = 0.f;
    er[1] = c;   ei[1] = -s;
    er[2] = er[1]*er[1] - ei[1]*ei[1];  ei[2] = 2.f*er[1]*ei[1];
    er[3] = er[2]*er[1] - ei[2]*ei[1];  ei[3] = er[2]*ei[1] + ei[2]*er[1];
    const float rr1 = 0.999698818696204f, ri1 = -0.024541228522912f; // e^{-2pi i/256}
    const float rr2 = 0.998795456205172f, ri2 = -0.049067674327418f; // ^2
    const float rr3 = 0.997290456678690f, ri3 = -0.073564563599667f; // ^3
    orE[0] = 1.f; oiE[0] = 0.f;
    orE[1] = er[1]*rr1 - ei[1]*ri1;  oiE[1] = er[1]*ri1 + ei[1]*rr1;
    orE[2] = er[2]*rr2 - ei[2]*ri2;  oiE[2] = er[2]*ri2 + ei[2]*rr2;
    orE[3] = er[3]*rr3 - ei[3]*ri3;  oiE[3] = er[3]*ri3 + ei[3]*rr3;

    int midx = lane >> 3;
    float mf = (midx < 4) ? (float)midx : (float)(midx - 8);
    float snm, csm;
    sincosf((PI2 / 256.0f) * mf * (float)y0, &snm, &csm);
    float cs = csm, ty = -snm;
    float smm, cmm;
    sincosf((PI2 / 256.0f) * mf, &smm, &cmm);   // rotation per +1 row

    float acc = 0.f;
#pragma unroll
    for (int r = 0; r < 4; ++r) {
        float s0 = A0[r][0] + A1[r][0], d0 = A0[r][0] - A1[r][0];
        float s2 = A0[r][2] + A1[r][2], d2 = A0[r][2] - A1[r][2];
        float ar[4], ai[4];
#pragma unroll
        for (int kw = 0; kw < 4; ++kw) {
            float E = (kw & 1) ? d0 : s0;      // tw(t+128)^kw = (-1)^kw tw(t)^kw
            float O = (kw & 1) ? d2 : s2;
            ar[kw] = E * er[kw] + O * orE[kw];
            ai[kw] = E * ei[kw] + O * oiE[kw];
        }
        float C  = fold8(ar, ai, lane);
        float pt = __shfl_xor(C, 1, 64);
        float sel = (lane & 1) ? ty : -ty;
        acc += C * cs + pt * sel;
        float nc = cs * cmm + ty * smm;
        float nt = ty * cmm - cs * smm;
        cs = nc; ty = nt;
    }
    vals[w][lane] = acc;
    __syncthreads();

    if (threadIdx.x < 64) {
        int b = bc >> 3, ci = bc & 7;
        float sum = vals[0][lane] + vals[1][lane] + vals[2][lane] + vals[3][lane];
        Yg[((size_t)((b * 16 + g) * 8 + ci)) * 64 + lane] = sum;
    }
}

// ---- K_B: block = (bo, chunk<32). Phase 1: c2 from Yg. Phase 2: eval 8 z. ----
__global__ __launch_bounds__(256) void k_mix_eval(const float* __restrict__ Yg,
                                                  const float* __restrict__ w1,
                                                  const float* __restrict__ w2,
                                                  float* __restrict__ out) {
    __shared__ float vals[4][64];
    __shared__ float lcf[64];     // c2[midx*8+kw*2+ri], indexed by lane role

    int lane  = threadIdx.x & 63;
    int w     = threadIdx.x >> 6;           // wave 0..3
    int bo    = blockIdx.x >> 5;            // b*8+o
    int chunk = blockIdx.x & 31;
    int b = bo >> 3, o = bo & 7;

    // ---- Phase 1: lane role (midx,kw,ri); sum over g (strided by wave) and ci
    {
        int midx = lane >> 3, kw = (lane >> 1) & 3, ri = lane & 1, mx = midx & 3;
        const float* wt = (midx < 4) ? w1 : w2;
        float wr_[8], swi_[8];
#pragma unroll
        for (int ci = 0; ci < 8; ++ci) {
            const float* wp = wt + ((((ci * 8 + o) * 4 + mx) * 4 + kw) * 2);
            wr_[ci]  = wp[0];
            swi_[ci] = ri ? wp[1] : -wp[1];
        }
        float acc = 0.f;
#pragma unroll
        for (int gi = 0; gi < 4; ++gi) {
            int g = w + gi * 4;
            const float* Yp = Yg + ((size_t)((b * 16 + g) * 8)) * 64 + lane;
#pragma unroll
            for (int ci = 0; ci < 8; ++ci) {
                float Yv = Yp[ci * 64];
                float pt = __shfl_xor(Yv, 1, 64);
                acc += Yv * wr_[ci] + pt * swi_[ci];
            }
        }
        vals[w][lane] = acc;
    }
    __syncthreads();
    if (w == 0)
        lcf[lane] = vals[0][lane] + vals[1][lane] + vals[2][lane] + vals[3][lane];
    __syncthreads();

    // ---- Phase 2: eval. 2 z-tasks per wave; task covers rows z and z+256. ----
    float c1b, s1b;
    sincosf((PI2 / 512.0f) * (float)(lane * 4), &s1b, &c1b);
    const float cr = 0.99992470183839f;     // cos(2pi/512)
    const float sr = 0.012271538285720f;    // sin(2pi/512)
    const float inv = 1.0f / 65536.0f;

    int ll = lane & 31;
    int kw = ll & 3, midx = (ll >> 2) & 7;
    float m = (midx < 4) ? (float)midx : (float)(midx - 8);
    float2 cc = make_float2(lcf[ll * 2], lcf[ll * 2 + 1]);
    float sgm = (midx & 1) ? -1.f : 1.f;

#pragma unroll
    for (int e = 0; e < 2; ++e) {
        int z = chunk * 8 + w * 2 + e;      // [0,256)

        float ang = (PI2 / 512.0f) * m * (float)z;
        float s, c;
        sincosf(ang, &s, &c);
        float hx = cc.x * c - cc.y * s;
        float hy = cc.x * s + cc.y * c;
        float gx = sgm * hx, gy = sgm * hy;

        float F = foldred(hx, hy, 4, lane);
        F += __shfl_xor(F, 8, 64);
        F += __shfl_xor(F, 16, 64);
        float G = foldred(gx, gy, 4, lane);
        G += __shfl_xor(G, 8, 64);
        G += __shfl_xor(G, 16, 64);
        float h0x = __shfl(F, 0, 64);
        float h1x = __shfl(F, 1, 64), h2x = __shfl(F, 2, 64), h3x = __shfl(F, 3, 64);
        float h1y = __shfl(F, 5, 64), h2y = __shfl(F, 6, 64), h3y = __shfl(F, 7, 64);
        float g0x = __shfl(G, 0, 64);
        float g1x = __shfl(G, 1, 64), g2x = __shfl(G, 2, 64), g3x = __shfl(G, 3, 64);
        float g1y = __shfl(G, 5, 64), g2y = __shfl(G, 6, 64), g3y = __shfl(G, 7, 64);

        float* orow0 = out + (size_t)(bo * 512 + z) * 512;
        float* orow1 = orow0 + 256 * 512;

        float c1 = c1b, s1 = s1b;
        vfloat4 r0, r1, q0, q1;
#pragma unroll
        for (int j = 0; j < 4; ++j) {
            float c2a = c1 * c1 - s1 * s1, s2a = 2.f * c1 * s1;
            float c3a = c2a * c1 - s2a * s1, s3a = s2a * c1 + c2a * s1;
            float t1 = h1x * c1  - h1y * s1;
            float t2 = h2x * c2a - h2y * s2a;
            float t3 = h3x * c3a - h3y * s3a;
            r0[j] = (h0x + t1 + t2 + t3) * inv;
            r1[j] = (h0x - t1 + t2 - t3) * inv;
            float u1 = g1x * c1  - g1y * s1;
            float u2 = g2x * c2a - g2y * s2a;
            float u3 = g3x * c3a - g3y * s3a;
            q0[j] = (g0x + u1 + u2 + u3) * inv;
            q1[j] = (g0x - u1 + u2 - u3) * inv;
            float nc = c1 * cr - s1 * sr;
            float ns = s1 * cr + c1 * sr;
            c1 = nc; s1 = ns;
        }
        __builtin_nontemporal_store(r0, (vfloat4*)(orow0 + lane * 4));
        __builtin_nontemporal_store(r1, (vfloat4*)(orow0 + 256 + lane * 4));
        __builtin_nontemporal_store(q0, (vfloat4*)(orow1 + lane * 4));
        __builtin_nontemporal_store(q1, (vfloat4*)(orow1 + 256 + lane * 4));
    }
}

extern "C" void kernel_launch(void* const* d_in, const int* in_sizes, int n_in,
                              void* d_out, int out_size, void* d_ws, size_t ws_size,
                              hipStream_t stream) {
    const float* x  = (const float*)d_in[0];
    const float* w1 = (const float*)d_in[3];
    const float* w2 = (const float*)d_in[4];
    float* out = (float*)d_out;

    float* Yg = (float*)d_ws;               // [8][16][8][64] floats = 256 KB

    k_dft_t<<<1024, 256, 0, stream>>>(x, Yg);
    // MEASUREMENT: second identical launch is idempotent (rewrites same values).
    // dur - 25.6us ~= T(k_mix_eval) + ~1us boundary.
    k_mix_eval<<<2048, 256, 0, stream>>>(Yg, w1, w2, out);
    k_mix_eval<<<2048, 256, 0, stream>>>(Yg, w1, w2, out);
}

// Round 17
// 24.435 us; speedup vs baseline: 1.6183x; 1.6183x over previous
//
#include <hip/hip_runtime.h>
#include <hip/hip_bf16.h>

// Problem: B=8, CIN=8, COUT=8, NX=NT=512, M1=M2=4.
// out[b,o,z,i] = Re( sum_{m,kw} c2[b,o,m,kw] e^{2pi i (m z + kw i)/512} ) / 65536
// R17: R13 structure + ALL sincosf replaced by HW v_sin/v_cos (input in
// REVOLUTIONS, exact r=k/2^n arguments). lib sincosf (no -ffast-math) is
// ~50-80 VALU ops; both kernels measured ~2x over memory floor (R16:
// T_mix_eval~13us, T_dft_t~11.5us) -> VALU-bound hypothesis.
// Ledger: NT stores +4us (R11); kernel split -2us (R12); grid.sync ~100us (R5);
// fused atomics neutral (R14/R15); R13=R14=R15=25.6.

#define PI2 6.283185307179586f

typedef float vfloat4 __attribute__((ext_vector_type(4)));

// sin/cos of 2*pi*r via HW trans ops (v_sin_f32 input is revolutions).
__device__ __forceinline__ void fsincos(float r, float* s, float* c) {
    r = r - floorf(r);
    *s = __builtin_amdgcn_sinf(r);
    *c = __builtin_amdgcn_cosf(r);
}

// fold-reduce: lanes with (lane&msk)==0 end holding u+partner_u; lanes with
// (lane&msk)!=0 end holding v+partner_v.
__device__ __forceinline__ float foldred(float u, float v, int msk, int lane) {
    float send = (lane & msk) ? u : v;
    float recv = __shfl_xor(send, msk, 64);
    return ((lane & msk) ? v : u) + recv;
}

// full fold of 4 complex accumulators -> every lane holds (kw=(l>>1)&3, ri=l&1)
__device__ __forceinline__ float fold8(const float* ar, const float* ai, int lane) {
    float A0 = foldred(ar[0], ai[0], 1, lane);
    float A1 = foldred(ar[1], ai[1], 1, lane);
    float A2 = foldred(ar[2], ai[2], 1, lane);
    float A3 = foldred(ar[3], ai[3], 1, lane);
    float B0 = foldred(A0, A1, 2, lane);
    float B1 = foldred(A2, A3, 2, lane);
    float C  = foldred(B0, B1, 4, lane);
    C += __shfl_xor(C, 8, 64);
    C += __shfl_xor(C, 16, 64);
    C += __shfl_xor(C, 32, 64);
    return C;
}

// ---- K_A: t-DFT + y-twiddle, 4 rows per wave, 16-row block sum. 1024x256. ----
__global__ __launch_bounds__(256) void k_dft_t(const float* __restrict__ x,
                                               float* __restrict__ Yg) {
    __shared__ float vals[4][64];
    int lane = threadIdx.x & 63;
    int w    = threadIdx.x >> 6;         // 0..3
    int bc   = blockIdx.x >> 4;          // b*8+ci
    int g    = blockIdx.x & 15;
    int y0   = g * 16 + w * 4;           // this wave: xs-rows y0..y0+3

    const float* base = x + (size_t)bc * 512 * 512;

    vfloat4 A0[4], A1[4];
#pragma unroll
    for (int r = 0; r < 4; ++r) {
        const vfloat4* row = (const vfloat4*)(base + (size_t)(2 * (y0 + r)) * 512);
        A0[r] = __builtin_nontemporal_load(&row[lane]);
        A1[r] = __builtin_nontemporal_load(&row[lane + 64]);
    }

    // twE = e^{-2pi i (2L)/256} = e^{-2pi i L/128}
    float s, c;
    fsincos((float)lane * 0.0078125f, &s, &c);      // lane/128, exact
    float er[4], ei[4], orE[4], oiE[4];
    er[0] = 1.f; ei[0] = 0.f;
    er[1] = c;   ei[1] = -s;
    er[2] = er[1]*er[1] - ei[1]*ei[1];  ei[2] = 2.f*er[1]*ei[1];
    er[3] = er[2]*er[1] - ei[2]*ei[1];  ei[3] = er[2]*ei[1] + ei[2]*er[1];
    const float rr1 = 0.999698818696204f, ri1 = -0.024541228522912f; // e^{-2pi i/256}
    const float rr2 = 0.998795456205172f, ri2 = -0.049067674327418f; // ^2
    const float rr3 = 0.997290456678690f, ri3 = -0.073564563599667f; // ^3
    orE[0] = 1.f; oiE[0] = 0.f;
    orE[1] = er[1]*rr1 - ei[1]*ri1;  oiE[1] = er[1]*ri1 + ei[1]*rr1;
    orE[2] = er[2]*rr2 - ei[2]*ri2;  oiE[2] = er[2]*ri2 + ei[2]*rr2;
    orE[3] = er[3]*rr3 - ei[3]*ri3;  oiE[3] = er[3]*ri3 + ei[3]*rr3;

    int midx = lane >> 3;
    float mf = (midx < 4) ? (float)midx : (float)(midx - 8);
    float snm, csm;
    fsincos(mf * (float)y0 * 0.00390625f, &snm, &csm);   // m*y0/256, exact
    float cs = csm, ty = -snm;
    float smm, cmm;
    fsincos(mf * 0.00390625f, &smm, &cmm);               // m/256, rotation per +1 row

    float acc = 0.f;
#pragma unroll
    for (int r = 0; r < 4; ++r) {
        float s0 = A0[r][0] + A1[r][0], d0 = A0[r][0] - A1[r][0];
        float s2 = A0[r][2] + A1[r][2], d2 = A0[r][2] - A1[r][2];
        float ar[4], ai[4];
#pragma unroll
        for (int kw = 0; kw < 4; ++kw) {
            float E = (kw & 1) ? d0 : s0;      // tw(t+128)^kw = (-1)^kw tw(t)^kw
            float O = (kw & 1) ? d2 : s2;
            ar[kw] = E * er[kw] + O * orE[kw];
            ai[kw] = E * ei[kw] + O * oiE[kw];
        }
        float C  = fold8(ar, ai, lane);
        float pt = __shfl_xor(C, 1, 64);
        float sel = (lane & 1) ? ty : -ty;
        acc += C * cs + pt * sel;
        float nc = cs * cmm + ty * smm;
        float nt = ty * cmm - cs * smm;
        cs = nc; ty = nt;
    }
    vals[w][lane] = acc;
    __syncthreads();

    if (threadIdx.x < 64) {
        int b = bc >> 3, ci = bc & 7;
        float sum = vals[0][lane] + vals[1][lane] + vals[2][lane] + vals[3][lane];
        Yg[((size_t)((b * 16 + g) * 8 + ci)) * 64 + lane] = sum;
    }
}

// ---- K_B: block = (bo, chunk<32). Phase 1: c2 from Yg. Phase 2: eval 8 z. ----
__global__ __launch_bounds__(256) void k_mix_eval(const float* __restrict__ Yg,
                                                  const float* __restrict__ w1,
                                                  const float* __restrict__ w2,
                                                  float* __restrict__ out) {
    __shared__ float vals[4][64];
    __shared__ float lcf[64];     // c2[midx*8+kw*2+ri], indexed by lane role

    int lane  = threadIdx.x & 63;
    int w     = threadIdx.x >> 6;           // wave 0..3
    int bo    = blockIdx.x >> 5;            // b*8+o
    int chunk = blockIdx.x & 31;
    int b = bo >> 3, o = bo & 7;

    // ---- Phase 1: lane role (midx,kw,ri); sum over g (strided by wave) and ci
    {
        int midx = lane >> 3, kw = (lane >> 1) & 3, ri = lane & 1, mx = midx & 3;
        const float* wt = (midx < 4) ? w1 : w2;
        float wr_[8], swi_[8];
#pragma unroll
        for (int ci = 0; ci < 8; ++ci) {
            const float* wp = wt + ((((ci * 8 + o) * 4 + mx) * 4 + kw) * 2);
            wr_[ci]  = wp[0];
            swi_[ci] = ri ? wp[1] : -wp[1];
        }
        float acc = 0.f;
#pragma unroll
        for (int gi = 0; gi < 4; ++gi) {
            int g = w + gi * 4;
            const float* Yp = Yg + ((size_t)((b * 16 + g) * 8)) * 64 + lane;
#pragma unroll
            for (int ci = 0; ci < 8; ++ci) {
                float Yv = Yp[ci * 64];
                float pt = __shfl_xor(Yv, 1, 64);
                acc += Yv * wr_[ci] + pt * swi_[ci];
            }
        }
        vals[w][lane] = acc;
    }
    __syncthreads();
    if (w == 0)
        lcf[lane] = vals[0][lane] + vals[1][lane] + vals[2][lane] + vals[3][lane];
    __syncthreads();

    // ---- Phase 2: eval. 2 z-tasks per wave; task covers rows z and z+256. ----
    float c1b, s1b;
    fsincos((float)lane * 0.0078125f, &s1b, &c1b);   // lane*4/512 = lane/128, exact
    const float cr = 0.99992470183839f;     // cos(2pi/512)
    const float sr = 0.012271538285720f;    // sin(2pi/512)
    const float inv = 1.0f / 65536.0f;

    int ll = lane & 31;
    int kw = ll & 3, midx = (ll >> 2) & 7;
    float m = (midx < 4) ? (float)midx : (float)(midx - 8);
    float2 cc = make_float2(lcf[ll * 2], lcf[ll * 2 + 1]);
    float sgm = (midx & 1) ? -1.f : 1.f;

#pragma unroll
    for (int e = 0; e < 2; ++e) {
        int z = chunk * 8 + w * 2 + e;      // [0,256)

        float s, c;
        fsincos(m * (float)z * 0.001953125f, &s, &c);   // m*z/512, exact
        float hx = cc.x * c - cc.y * s;
        float hy = cc.x * s + cc.y * c;
        float gx = sgm * hx, gy = sgm * hy;

        float F = foldred(hx, hy, 4, lane);
        F += __shfl_xor(F, 8, 64);
        F += __shfl_xor(F, 16, 64);
        float G = foldred(gx, gy, 4, lane);
        G += __shfl_xor(G, 8, 64);
        G += __shfl_xor(G, 16, 64);
        float h0x = __shfl(F, 0, 64);
        float h1x = __shfl(F, 1, 64), h2x = __shfl(F, 2, 64), h3x = __shfl(F, 3, 64);
        float h1y = __shfl(F, 5, 64), h2y = __shfl(F, 6, 64), h3y = __shfl(F, 7, 64);
        float g0x = __shfl(G, 0, 64);
        float g1x = __shfl(G, 1, 64), g2x = __shfl(G, 2, 64), g3x = __shfl(G, 3, 64);
        float g1y = __shfl(G, 5, 64), g2y = __shfl(G, 6, 64), g3y = __shfl(G, 7, 64);

        float* orow0 = out + (size_t)(bo * 512 + z) * 512;
        float* orow1 = orow0 + 256 * 512;

        float c1 = c1b, s1 = s1b;
        vfloat4 r0, r1, q0, q1;
#pragma unroll
        for (int j = 0; j < 4; ++j) {
            float c2a = c1 * c1 - s1 * s1, s2a = 2.f * c1 * s1;
            float c3a = c2a * c1 - s2a * s1, s3a = s2a * c1 + c2a * s1;
            float t1 = h1x * c1  - h1y * s1;
            float t2 = h2x * c2a - h2y * s2a;
            float t3 = h3x * c3a - h3y * s3a;
            r0[j] = (h0x + t1 + t2 + t3) * inv;
            r1[j] = (h0x - t1 + t2 - t3) * inv;
            float u1 = g1x * c1  - g1y * s1;
            float u2 = g2x * c2a - g2y * s2a;
            float u3 = g3x * c3a - g3y * s3a;
            q0[j] = (g0x + u1 + u2 + u3) * inv;
            q1[j] = (g0x - u1 + u2 - u3) * inv;
            float nc = c1 * cr - s1 * sr;
            float ns = s1 * cr + c1 * sr;
            c1 = nc; s1 = ns;
        }
        __builtin_nontemporal_store(r0, (vfloat4*)(orow0 + lane * 4));
        __builtin_nontemporal_store(r1, (vfloat4*)(orow0 + 256 + lane * 4));
        __builtin_nontemporal_store(q0, (vfloat4*)(orow1 + lane * 4));
        __builtin_nontemporal_store(q1, (vfloat4*)(orow1 + 256 + lane * 4));
    }
}

extern "C" void kernel_launch(void* const* d_in, const int* in_sizes, int n_in,
                              void* d_out, int out_size, void* d_ws, size_t ws_size,
                              hipStream_t stream) {
    const float* x  = (const float*)d_in[0];
    const float* w1 = (const float*)d_in[3];
    const float* w2 = (const float*)d_in[4];
    float* out = (float*)d_out;

    float* Yg = (float*)d_ws;               // [8][16][8][64] floats = 256 KB

    k_dft_t<<<1024, 256, 0, stream>>>(x, Yg);
    k_mix_eval<<<2048, 256, 0, stream>>>(Yg, w1, w2, out);
}